// Round 8
// baseline (211.926 us; speedup 1.0000x reference)
//
#include <hip/hip_runtime.h>
#include <hip/hip_bf16.h>

typedef __attribute__((ext_vector_type(8))) short short8;
typedef __attribute__((ext_vector_type(4))) float f32x4;
typedef __attribute__((ext_vector_type(16))) float f32x16;

#define WS_B0_OFFSET  18874368u   // b0 after Wt2 (9*1024*1024 bf16)

// -------- Phase 0a: W[d][i][o] fp32 -> Wt2[(d*128+q)][o][j] bf16 (i = q*8+j) --------
__global__ void wt2_kernel(const float* __restrict__ W, short* __restrict__ Wt2) {
    int bid = blockIdx.x;            // 0..1151
    int d = bid >> 7, q = bid & 127;
    int t = threadIdx.x;             // 256
    const float* src = W + (size_t)d * 1048576 + (size_t)q * 8 * 1024;
    short* dst = Wt2 + ((size_t)(d * 128 + q) << 13);
#pragma unroll
    for (int u = 0; u < 4; u++) {
        int o = u * 256 + t;
        short8 v;
#pragma unroll
        for (int j = 0; j < 8; j++)
            v[j] = (short)__bfloat16_as_ushort(__float2bfloat16(src[(size_t)j * 1024 + o]));
        *(short8*)(dst + (size_t)o * 8) = v;
    }
}

// -------- Phase 0b: b0[o] = sum_i W[0][i][o], two-stage --------
__global__ void colsum1(const float* __restrict__ W, float* __restrict__ part) {
    int s = blockIdx.x >> 2;
    int o = (blockIdx.x & 3) * 256 + threadIdx.x;
    const float* p = W + (size_t)s * 32 * 1024 + o;
    float acc = 0.f;
#pragma unroll
    for (int i = 0; i < 32; i++) acc += p[(size_t)i * 1024];
    part[s * 1024 + o] = acc;
}
__global__ void colsum2(const float* __restrict__ part, float* __restrict__ b0) {
    int o = blockIdx.x * 256 + threadIdx.x;
    float acc = 0.f;
#pragma unroll
    for (int s = 0; s < 32; s++) acc += part[s * 1024 + o];
    b0[o] = acc;
}

__device__ __forceinline__ float fast_tanh(float t) {
    float e = __expf(t + t);
    return 1.0f - 2.0f * __builtin_amdgcn_rcpf(e + 1.0f);
}

// -------- Phase 1: fused tanh + Chebyshev + GEMM, barrier-light, A-in-registers ----
// 256 thr = 4 waves, tile 128x128, BK=16, grid 512 = 2 blocks/CU.
// Wave = 128 rows x 32 cols: lane owns A rows m*32+(lane&31), k-chunk (lane>>5)*8
// == exactly the mfma_32x32x16 A-fragment, so af = cvt8(recurrence regs): A never
// touches LDS. B loaded direct from XCD-L2 (tn = bid&7 = XCD id), 1 step ahead.
// LDS only holds xt (tanh output, 8KB, granule-XOR swizzle); 2 barriers / 8 steps.
extern "C" __global__ void __launch_bounds__(256, 2)
cheby_gemm(const float* __restrict__ x, const short* __restrict__ Wt2,
           const float* __restrict__ b0v, const float* __restrict__ scp,
           const float* __restrict__ bip, float* __restrict__ out) {
    __shared__ __align__(16) char xt[8192];   // [row 0..127][16 k fp32], swizzled

    const int tid = threadIdx.x, lane = tid & 63, wid = tid >> 6;
    const int tn = blockIdx.x & 7, tm = blockIdx.x >> 3;
    const int m0 = tm << 7, n0 = tn << 7;
    const float sc = scp[0], bi = bip[0];
    const char* wtb = (const char*)Wt2;

    // xt write ownership: row = tid>>1, 8 elems at k = (tid&1)*8 (granules xg0, xg0+1)
    const int xrow = tid >> 1, xg0 = (tid & 1) << 1;
    const int xs = (xrow >> 1) & 3;                  // granule swizzle key
    char* wp0 = xt + xrow * 64 + ((xg0 ^ xs) << 4);
    char* wp1 = xt + xrow * 64 + (((xg0 + 1) ^ xs) << 4);
    const float* xptr = x + (size_t)(m0 + xrow) * 1024 + (xg0 << 2);

    // xt read offsets: per m-block, row = m*32+(lane&31), granules 2c, 2c+1
    const int c = lane >> 5;
    int rdo[4][2];
#pragma unroll
    for (int m = 0; m < 4; m++) {
        int row = m * 32 + (lane & 31);
        int s = (row >> 1) & 3;
#pragma unroll
        for (int h = 0; h < 2; h++)
            rdo[m][h] = row * 64 + ((((c << 1) + h) ^ s) << 4);
    }
    // B fragment byte offset (col = n0 + wid*32 + lane&31, chunk c)
    const int bofs = (c << 14) + ((n0 + (wid << 5) + (lane & 31)) << 4);

    auto bld = [&](int dd, int icc) -> short8 {
        return *(const short8*)(wtb + (((size_t)(dd << 7) + (icc << 1)) << 14) + bofs);
    };

    f32x4 xv0, xv1;
    auto loadx = [&](int icc) {
        const float* p = xptr + (icc << 4);
        xv0 = *(const f32x4*)p;
        xv1 = *(const f32x4*)(p + 4);
    };
    auto tanh_store = [&]() {
        f32x4 a, b;
#pragma unroll
        for (int j = 0; j < 4; j++) {
            a[j] = fast_tanh(fmaf(xv0[j], sc, bi));
            b[j] = fast_tanh(fmaf(xv1[j], sc, bi));
        }
        *(f32x4*)wp0 = a;
        *(f32x4*)wp1 = b;
    };

    float tAv[4][8], tBv[4][8], x2v[4][8];
    short8 afA[4], afB[4], bfA, bfB;

    auto cvt8 = [&](const float* t) -> short8 {
        short8 r;
#pragma unroll
        for (int j = 0; j < 8; j++)
            r[j] = (short)__bfloat16_as_ushort(__float2bfloat16(t[j]));
        return r;
    };

    f32x16 acc[4];
    {
        float v = b0v[n0 + (wid << 5) + (lane & 31)];   // degree-0 folded in
        f32x16 a;
#pragma unroll
        for (int r = 0; r < 16; r++) a[r] = v;
#pragma unroll
        for (int m = 0; m < 4; m++) acc[m] = a;
    }

    auto burst = [&](const short8* af, short8 bf) {
        __builtin_amdgcn_s_setprio(1);
#pragma unroll
        for (int m = 0; m < 4; m++)
            acc[m] = __builtin_amdgcn_mfma_f32_32x32x16_bf16(af[m], bf, acc[m], 0, 0, 0);
        __builtin_amdgcn_s_setprio(0);
    };

#define BAR  __builtin_amdgcn_sched_barrier(0);                      \
             __builtin_amdgcn_s_barrier();                           \
             __builtin_amdgcn_sched_barrier(0);
#define BARW __builtin_amdgcn_sched_barrier(0);                      \
             asm volatile("s_waitcnt lgkmcnt(0)" ::: "memory");      \
             __builtin_amdgcn_s_barrier();                           \
             __builtin_amdgcn_sched_barrier(0);

    // ---- prologue: tanh(ic=0) -> xt; B(d=1, 0) -> bfA ----
    loadx(0);
    bfA = bld(1, 0);
    tanh_store();
    BARW

    for (int ic = 0; ic < 64; ++ic) {
        const int icn = ic < 63 ? ic + 1 : 63;
        { // d=1: read xt -> T1, x2; MFMA(T1); then T2
            bfB = bld(2, ic);
#pragma unroll
            for (int m = 0; m < 4; m++) {
                f32x4 lo = *(const f32x4*)(xt + rdo[m][0]);
                f32x4 hi = *(const f32x4*)(xt + rdo[m][1]);
#pragma unroll
                for (int j = 0; j < 4; j++) { tAv[m][j] = lo[j]; tAv[m][4 + j] = hi[j]; }
#pragma unroll
                for (int j = 0; j < 8; j++) x2v[m][j] = tAv[m][j] + tAv[m][j];
                afA[m] = cvt8(tAv[m]);
            }
            burst(afA, bfA);
#pragma unroll
            for (int m = 0; m < 4; m++) {
#pragma unroll
                for (int j = 0; j < 8; j++) tBv[m][j] = fmaf(x2v[m][j], tAv[m][j], -1.0f);
                afB[m] = cvt8(tBv[m]);
            }
            BAR   // xt reads consumed; next writer (d=8) is past this barrier
        }
#define RSTEP(AFU, BFU, BFL, LD, DST, SRC, AFN, XPRE)                 \
        {                                                             \
            burst(AFU, BFU);                                          \
            BFL = bld(LD, ic);                                        \
            if (XPRE) loadx(icn);                                     \
_Pragma("unroll")                                                     \
            for (int m = 0; m < 4; m++) {                             \
_Pragma("unroll")                                                     \
                for (int j = 0; j < 8; j++)                           \
                    DST[m][j] = fmaf(x2v[m][j], SRC[m][j], -DST[m][j]); \
                AFN[m] = cvt8(DST[m]);                                \
            }                                                         \
        }
        RSTEP(afB, bfB, bfA, 3, tAv, tBv, afA, 0)   // d=2: make T3
        RSTEP(afA, bfA, bfB, 4, tBv, tAv, afB, 0)   // d=3: make T4
        RSTEP(afB, bfB, bfA, 5, tAv, tBv, afA, 0)   // d=4: make T5
        RSTEP(afA, bfA, bfB, 6, tBv, tAv, afB, 0)   // d=5: make T6
        RSTEP(afB, bfB, bfA, 7, tAv, tBv, afA, 1)   // d=6: make T7; prefetch x'
        RSTEP(afA, bfA, bfB, 8, tBv, tAv, afB, 0)   // d=7: make T8
#undef RSTEP
        { // d=8: MFMA(T8); load B(d=1, ic+1); tanh(x') -> xt
            burst(afB, bfB);
            bfA = bld(1, icn);
            tanh_store();
            BARW   // ds_writes visible before next d=1 reads
        }
    }
#undef BAR
#undef BARW

    // ---- epilogue: C/D col=lane&31, row=(r&3)+8*(r>>2)+4*(lane>>5) ----
    {
        int colg = n0 + (wid << 5) + (lane & 31);
#pragma unroll
        for (int m = 0; m < 4; m++) {
            int rbase = m0 + m * 32 + ((lane >> 5) << 2);
#pragma unroll
            for (int r = 0; r < 16; r++) {
                int rowg = rbase + (r & 3) + 8 * (r >> 2);
                out[(size_t)rowg * 1024 + colg] = acc[m][r];
            }
        }
    }
}

extern "C" void kernel_launch(void* const* d_in, const int* in_sizes, int n_in,
                              void* d_out, int out_size, void* d_ws, size_t ws_size,
                              hipStream_t stream) {
    const float* x  = (const float*)d_in[0];
    const float* W  = (const float*)d_in[1];
    const float* sc = (const float*)d_in[2];
    const float* bi = (const float*)d_in[3];
    float* out = (float*)d_out;

    short* Wt2 = (short*)d_ws;
    float* b0  = (float*)((char*)d_ws + WS_B0_OFFSET);
    float* part = out;   // colsum partials staged in d_out (fully overwritten by gemm)

    hipLaunchKernelGGL(wt2_kernel, dim3(9 * 128), dim3(256), 0, stream, W, Wt2);
    hipLaunchKernelGGL(colsum1, dim3(128), dim3(256), 0, stream, W, part);
    hipLaunchKernelGGL(colsum2, dim3(4), dim3(256), 0, stream, part, b0);
    hipLaunchKernelGGL(cheby_gemm, dim3(512), dim3(256), 0, stream, x, Wt2, b0, sc, bi, out);
}

// Round 9
// 208.395 us; speedup vs baseline: 1.0169x; 1.0169x over previous
//
#include <hip/hip_runtime.h>
#include <hip/hip_bf16.h>

typedef __attribute__((ext_vector_type(8))) short short8;
typedef __attribute__((ext_vector_type(4))) float f32x4;
typedef __attribute__((ext_vector_type(16))) float f32x16;

#define WS_B0_OFFSET  18874368u   // b0 after Wt2 (9*1024*1024 bf16)

// -------- Phase 0a: W[d][i][o] fp32 -> Wt2[(d*128+q)][o][j] bf16 (i = q*8+j) --------
__global__ void wt2_kernel(const float* __restrict__ W, short* __restrict__ Wt2) {
    int bid = blockIdx.x;            // 0..1151
    int d = bid >> 7, q = bid & 127;
    int t = threadIdx.x;             // 256
    const float* src = W + (size_t)d * 1048576 + (size_t)q * 8 * 1024;
    short* dst = Wt2 + ((size_t)(d * 128 + q) << 13);
#pragma unroll
    for (int u = 0; u < 4; u++) {
        int o = u * 256 + t;
        short8 v;
#pragma unroll
        for (int j = 0; j < 8; j++)
            v[j] = (short)__bfloat16_as_ushort(__float2bfloat16(src[(size_t)j * 1024 + o]));
        *(short8*)(dst + (size_t)o * 8) = v;
    }
}

// -------- Phase 0b: b0[o] = sum_i W[0][i][o], two-stage --------
__global__ void colsum1(const float* __restrict__ W, float* __restrict__ part) {
    int s = blockIdx.x >> 2;
    int o = (blockIdx.x & 3) * 256 + threadIdx.x;
    const float* p = W + (size_t)s * 32 * 1024 + o;
    float acc = 0.f;
#pragma unroll
    for (int i = 0; i < 32; i++) acc += p[(size_t)i * 1024];
    part[s * 1024 + o] = acc;
}
__global__ void colsum2(const float* __restrict__ part, float* __restrict__ b0) {
    int o = blockIdx.x * 256 + threadIdx.x;
    float acc = 0.f;
#pragma unroll
    for (int s = 0; s < 32; s++) acc += part[s * 1024 + o];
    b0[o] = acc;
}

__device__ __forceinline__ float fast_tanh(float t) {
    float e = __expf(t + t);
    return 1.0f - 2.0f * __builtin_amdgcn_rcpf(e + 1.0f);
}

// -------- Phase 1: fused tanh + Chebyshev + GEMM, zero-LDS zero-barrier loop ----
// 256 thr = 4 waves, tile 128x128, BK=32, grid 512 = 2 blocks/CU.
// Wave = 32 rows x 128 cols. Thread owns A rows wid*32+(lane&31), k-chunks
// (lane>>5)*8 (+16) == exactly the mfma_32x32x16 A-fragment: recurrence state
// IS the A operand (no LDS, no duplication). B = 8 x global_load_dwordx4 per
// wave-step from the XCD-pinned L2 panel (L1 dedups the 4-wave re-read).
// Nothing shared -> no barriers; 2 blocks/CU drift anti-phase for pipe overlap.
extern "C" __global__ void __launch_bounds__(256, 2)
cheby_gemm(const float* __restrict__ x, const short* __restrict__ Wt2,
           const float* __restrict__ b0v, const float* __restrict__ scp,
           const float* __restrict__ bip, float* __restrict__ out) {
    const int tid = threadIdx.x, lane = tid & 63, wid = tid >> 6;
    const int tn = blockIdx.x & 7, tm = blockIdx.x >> 3;   // pair (b,b+256): same tn
    const int m0 = tm << 7, n0 = tn << 7;
    const float sc = scp[0], bi = bip[0];
    const char* wtb = (const char*)Wt2;

    // A ownership = fragment layout: row, k-chunk base
    const int arow = wid * 32 + (lane & 31);
    const int kc = (lane >> 5) << 3;                       // 0 or 8
    const float* xptr = x + (size_t)(m0 + arow) * 1024 + kc;

    // B fragment byte offsets: within-(d,ic) offset = (c*1024 + col)*16
    int bofs[4][2];
#pragma unroll
    for (int n = 0; n < 4; n++)
#pragma unroll
        for (int kh = 0; kh < 2; kh++) {
            int c = kh * 2 + (lane >> 5);
            bofs[n][kh] = (c << 14) + ((n0 + n * 32 + (lane & 31)) << 4);
        }

    short8 bf[4][2];
    auto bld = [&](int dd, int icc) {
        const char* p = wtb + ((size_t)dd << 21) + ((size_t)icc << 16);
#pragma unroll
        for (int n = 0; n < 4; n++)
#pragma unroll
            for (int kh = 0; kh < 2; kh++)
                bf[n][kh] = *(const short8*)(p + bofs[n][kh]);
    };

    f32x4 xv0, xv1, xv2, xv3;
    auto loadx = [&](int icc) {
        const float* p = xptr + (icc << 5);
        xv0 = *(const f32x4*)p;       xv1 = *(const f32x4*)(p + 4);
        xv2 = *(const f32x4*)(p + 16); xv3 = *(const f32x4*)(p + 20);
    };

    float x2[16], tA[16], tB[16];
    auto dotanh = [&]() {
#pragma unroll
        for (int j = 0; j < 4; j++) {
            tA[j]      = fast_tanh(fmaf(xv0[j], sc, bi));
            tA[j + 4]  = fast_tanh(fmaf(xv1[j], sc, bi));
            tA[j + 8]  = fast_tanh(fmaf(xv2[j], sc, bi));
            tA[j + 12] = fast_tanh(fmaf(xv3[j], sc, bi));
        }
#pragma unroll
        for (int j = 0; j < 16; j++) x2[j] = tA[j] + tA[j];
    };

    auto cvt8 = [](const float* t) -> short8 {
        short8 r;
#pragma unroll
        for (int j = 0; j < 8; j++)
            r[j] = (short)__bfloat16_as_ushort(__float2bfloat16(t[j]));
        return r;
    };

    f32x16 acc[4];
#pragma unroll
    for (int n = 0; n < 4; n++) {
        float v = b0v[n0 + n * 32 + (lane & 31)];          // degree-0 folded in
        f32x16 a;
#pragma unroll
        for (int r = 0; r < 16; r++) a[r] = v;
        acc[n] = a;
    }

    short8 afA[2], afB[2];
    auto burst = [&](const short8* af) {
        __builtin_amdgcn_s_setprio(1);
#pragma unroll
        for (int n = 0; n < 4; n++)
#pragma unroll
            for (int kh = 0; kh < 2; kh++)
                acc[n] = __builtin_amdgcn_mfma_f32_32x32x16_bf16(af[kh], bf[n][kh], acc[n], 0, 0, 0);
        __builtin_amdgcn_s_setprio(0);
    };

    // ---- prologue: tanh(ic0) -> T1 in regs ----
    loadx(0);
    dotanh();
    afA[0] = cvt8(tA); afA[1] = cvt8(tA + 8);

    for (int ic = 0; ic < 32; ++ic) {
        const int icn = ic < 31 ? ic + 1 : 31;
        { // s0 (d=1): make T2
            bld(1, ic);
#pragma unroll
            for (int j = 0; j < 16; j++) tB[j] = fmaf(x2[j], tA[j], -1.0f);
            afB[0] = cvt8(tB); afB[1] = cvt8(tB + 8);
            burst(afA);
        }
        { // s1 (d=2): make T3
            bld(2, ic);
#pragma unroll
            for (int j = 0; j < 16; j++) tA[j] = fmaf(x2[j], tB[j], -tA[j]);
            afA[0] = cvt8(tA); afA[1] = cvt8(tA + 8);
            burst(afB);
        }
#define RSTEP(D, DST, SRC, AFN, AFU, XPRE)                        \
        {                                                         \
            bld(D, ic);                                           \
            if (XPRE) loadx(icn);                                 \
_Pragma("unroll")                                                 \
            for (int j = 0; j < 16; j++)                          \
                DST[j] = fmaf(x2[j], SRC[j], -DST[j]);            \
            AFN[0] = cvt8(DST); AFN[1] = cvt8(DST + 8);           \
            burst(AFU);                                           \
        }
        RSTEP(3, tB, tA, afB, afA, 0)   // s2: d3, make T4
        RSTEP(4, tA, tB, afA, afB, 0)   // s3: d4, make T5
        RSTEP(5, tB, tA, afB, afA, 1)   // s4: d5, make T6; prefetch x'
        RSTEP(6, tA, tB, afA, afB, 0)   // s5: d6, make T7
        RSTEP(7, tB, tA, afB, afA, 0)   // s6: d7, make T8
#undef RSTEP
        { // s7 (d=8): MFMA(T8); tanh(x') -> T1'
            bld(8, ic);
            dotanh();
            afA[0] = cvt8(tA); afA[1] = cvt8(tA + 8);
            burst(afB);
        }
    }

    // ---- epilogue: C/D col=lane&31, row=(r&3)+8*(r>>2)+4*(lane>>5) ----
    {
        int rbase = m0 + wid * 32 + ((lane >> 5) << 2);
#pragma unroll
        for (int n = 0; n < 4; n++) {
            int colg = n0 + n * 32 + (lane & 31);
#pragma unroll
            for (int r = 0; r < 16; r++) {
                int rowg = rbase + (r & 3) + 8 * (r >> 2);
                out[(size_t)rowg * 1024 + colg] = acc[n][r];
            }
        }
    }
}

extern "C" void kernel_launch(void* const* d_in, const int* in_sizes, int n_in,
                              void* d_out, int out_size, void* d_ws, size_t ws_size,
                              hipStream_t stream) {
    const float* x  = (const float*)d_in[0];
    const float* W  = (const float*)d_in[1];
    const float* sc = (const float*)d_in[2];
    const float* bi = (const float*)d_in[3];
    float* out = (float*)d_out;

    short* Wt2 = (short*)d_ws;
    float* b0  = (float*)((char*)d_ws + WS_B0_OFFSET);
    float* part = out;   // colsum partials staged in d_out (fully overwritten by gemm)

    hipLaunchKernelGGL(wt2_kernel, dim3(9 * 128), dim3(256), 0, stream, W, Wt2);
    hipLaunchKernelGGL(colsum1, dim3(128), dim3(256), 0, stream, W, part);
    hipLaunchKernelGGL(colsum2, dim3(4), dim3(256), 0, stream, part, b0);
    hipLaunchKernelGGL(cheby_gemm, dim3(512), dim3(256), 0, stream, x, Wt2, b0, sc, bi, out);
}

// Round 10
// 151.162 us; speedup vs baseline: 1.4020x; 1.3786x over previous
//
#include <hip/hip_runtime.h>
#include <hip/hip_bf16.h>

typedef __attribute__((ext_vector_type(8))) short short8;
typedef __attribute__((ext_vector_type(4))) float f32x4;
typedef __attribute__((ext_vector_type(16))) float f32x16;

#define WS_B0_OFFSET  18874368u   // b0 after Wt2 (9*1024*1024 bf16)

// -------- Phase 0a: W[d][i][o] fp32 -> Wt2[(d*128+q)][o][j] bf16 (i = q*8+j) --------
__global__ void wt2_kernel(const float* __restrict__ W, short* __restrict__ Wt2) {
    int bid = blockIdx.x;            // 0..1151
    int d = bid >> 7, q = bid & 127;
    int t = threadIdx.x;             // 256
    const float* src = W + (size_t)d * 1048576 + (size_t)q * 8 * 1024;
    short* dst = Wt2 + ((size_t)(d * 128 + q) << 13);
#pragma unroll
    for (int u = 0; u < 4; u++) {
        int o = u * 256 + t;
        short8 v;
#pragma unroll
        for (int j = 0; j < 8; j++)
            v[j] = (short)__bfloat16_as_ushort(__float2bfloat16(src[(size_t)j * 1024 + o]));
        *(short8*)(dst + (size_t)o * 8) = v;
    }
}

// -------- Phase 0b: b0[o] = sum_i W[0][i][o], two-stage --------
__global__ void colsum1(const float* __restrict__ W, float* __restrict__ part) {
    int s = blockIdx.x >> 2;
    int o = (blockIdx.x & 3) * 256 + threadIdx.x;
    const float* p = W + (size_t)s * 32 * 1024 + o;
    float acc = 0.f;
#pragma unroll
    for (int i = 0; i < 32; i++) acc += p[(size_t)i * 1024];
    part[s * 1024 + o] = acc;
}
__global__ void colsum2(const float* __restrict__ part, float* __restrict__ b0) {
    int o = blockIdx.x * 256 + threadIdx.x;
    float acc = 0.f;
#pragma unroll
    for (int s = 0; s < 32; s++) acc += part[s * 1024 + o];
    b0[o] = acc;
}

__device__ __forceinline__ float fast_tanh(float t) {
    float e = __expf(t + t);
    return 1.0f - 2.0f * __builtin_amdgcn_rcpf(e + 1.0f);
}

// -------- Phase 1: fused tanh + Chebyshev + GEMM --------
// R4 geometry (512 thr = 8 waves: wc=wid&3 col slice, kh=wid>>2 K-half; tile
// 128x256, BK=32, grid 256 = 1 block/CU). NEW: 4 A-buffers, TWO degree-steps
// fused per barrier region, MFMA-first ordering so the recurrence VALU and the
// B-prefetch execute under the 16-MFMA matrix burst. 4 barriers/ic (was 8).
extern "C" __global__ void __launch_bounds__(512, 2)
cheby_gemm(const float* __restrict__ x, const short* __restrict__ Wt2,
           const float* __restrict__ b0v, const float* __restrict__ scp,
           const float* __restrict__ bip, float* __restrict__ out) {
    __shared__ __align__(16) char lds[65536];   // A bufs 4x8KB @0; merge 32KB @32768

    const int tid = threadIdx.x, lane = tid & 63, wid = tid >> 6;
    const int wc = wid & 3, kh = wid >> 2;
    const int tn = blockIdx.x & 3, tm = blockIdx.x >> 2;
    const int m0 = tm << 7, n0 = tn << 8;
    const float sc = scp[0], bi = bip[0];
    const char* wtb = (const char*)Wt2;

    // A ownership: row = tid>>2, chunk ac = tid&3 (8 k-elems)
    const int arow = tid >> 2, ac = tid & 3;
    const int wbyte0 = ac * 2048 + ((arow ^ (ac << 1)) << 4);
    const float* xptr = x + (size_t)(m0 + arow) * 1024 + ac * 8;

    // A-frag read base: chunk cfr = kh*2 + (lane>>5), rows m*32 + (lane&31)
    const int cfr = kh * 2 + (lane >> 5);
    const int abase = cfr * 2048 + (((lane & 31) ^ (cfr << 1)) << 4);
    // B byte offsets
    int bofs[2];
#pragma unroll
    for (int n = 0; n < 2; n++)
        bofs[n] = cfr * 16384 + (n0 + wc * 64 + n * 32 + (lane & 31)) * 16;

    auto bld = [&](short8* bf, int dd, int icc) {
        const char* p = wtb + ((size_t)(dd * 128 + icc * 4) << 14);
#pragma unroll
        for (int n = 0; n < 2; n++)
            bf[n] = *(const short8*)(p + bofs[n]);
    };

    f32x4 xv0, xv1;
    auto loadx = [&](int icc) {
        const float* p = xptr + (icc << 5);
        xv0 = *(const f32x4*)p;
        xv1 = *(const f32x4*)(p + 4);
    };

    float x2[8], tA[8], tB[8];
    auto dotanh = [&]() {
#pragma unroll
        for (int j = 0; j < 4; j++) {
            tA[j]     = fast_tanh(fmaf(xv0[j], sc, bi));
            tA[j + 4] = fast_tanh(fmaf(xv1[j], sc, bi));
        }
#pragma unroll
        for (int j = 0; j < 8; j++) x2[j] = tA[j] + tA[j];
    };
    auto writeA = [&](const float* t, int wbuf) {
        short8 v;
#pragma unroll
        for (int j = 0; j < 8; j++)
            v[j] = (short)__bfloat16_as_ushort(__float2bfloat16(t[j]));
        *(short8*)(lds + wbuf * 8192 + wbyte0) = v;
    };

    f32x16 acc[4][2];
#pragma unroll
    for (int n = 0; n < 2; n++) {
        float v = (kh == 0) ? b0v[n0 + wc * 64 + n * 32 + (lane & 31)] : 0.0f;
        f32x16 a;
#pragma unroll
        for (int r = 0; r < 16; r++) a[r] = v;
#pragma unroll
        for (int m = 0; m < 4; m++) acc[m][n] = a;
    }

    auto burst = [&](const short8* af, const short8* bf) {
        __builtin_amdgcn_s_setprio(1);
#pragma unroll
        for (int m = 0; m < 4; m++)
#pragma unroll
            for (int n = 0; n < 2; n++)
                acc[m][n] = __builtin_amdgcn_mfma_f32_32x32x16_bf16(af[m], bf[n], acc[m][n], 0, 0, 0);
        __builtin_amdgcn_s_setprio(0);
    };

    short8 bf0[2], bf1[2], bf2[2], bf3[2];

#define DRAIN_BAR                                                 \
    __builtin_amdgcn_sched_barrier(0);                            \
    asm volatile("s_waitcnt lgkmcnt(0)" ::: "memory");            \
    __builtin_amdgcn_s_barrier();                                 \
    __builtin_amdgcn_sched_barrier(0);

    // region: MFMA degrees (da in buf RA, db in buf RB) using BU0/BU1;
    // prefetch next degrees (LD0, LD1) into BL0/BL1; recurrence writes WA, WB.
#define REGION(RA, RB, BU0, BU1, BL0, BL1, LD0, LD1, LIC, XPRE, RECUR)  \
    {                                                                   \
        short8 afa[4], afb[4];                                          \
_Pragma("unroll")                                                       \
        for (int m = 0; m < 4; m++)                                     \
            afa[m] = *(const short8*)(lds + (RA) * 8192 + abase + m * 512); \
        burst(afa, BU0);                                                \
_Pragma("unroll")                                                       \
        for (int m = 0; m < 4; m++)                                     \
            afb[m] = *(const short8*)(lds + (RB) * 8192 + abase + m * 512); \
        burst(afb, BU1);                                                \
        bld(BL0, LD0, LIC); bld(BL1, LD1, LIC);                         \
        if (XPRE) loadx(icn);                                           \
        RECUR                                                           \
        DRAIN_BAR                                                       \
    }
#define REC_STD(WA, WB)                                                 \
    {                                                                   \
_Pragma("unroll")                                                       \
        for (int j = 0; j < 8; j++) tA[j] = fmaf(x2[j], tB[j], -tA[j]); \
        writeA(tA, WA);                                                 \
_Pragma("unroll")                                                       \
        for (int j = 0; j < 8; j++) tB[j] = fmaf(x2[j], tA[j], -tB[j]); \
        writeA(tB, WB);                                                 \
    }
#define REC_TANH(WA, WB)                                                \
    {                                                                   \
        dotanh();                                                       \
_Pragma("unroll")                                                       \
        for (int j = 0; j < 8; j++) tB[j] = fmaf(x2[j], tA[j], -1.0f);  \
        writeA(tA, WA);                                                 \
        writeA(tB, WB);                                                 \
    }

    // ---- prologue: T1,T2 -> bufs 1,2; B(d=1,2) -> bf0,bf1 ----
    loadx(0);
    bld(bf0, 1, 0); bld(bf1, 2, 0);
    dotanh();                                           // tA = T1
#pragma unroll
    for (int j = 0; j < 8; j++) tB[j] = fmaf(x2[j], tA[j], -1.0f);   // T2
    writeA(tA, 1); writeA(tB, 2);
    DRAIN_BAR

    for (int ic = 0; ic < 32; ++ic) {
        const int icn = ic < 31 ? ic + 1 : 31;
        REGION(1, 2, bf0, bf1, bf2, bf3, 3, 4, ic,  0, REC_STD(3, 0))   // d1,d2; make T3,T4
        REGION(3, 0, bf2, bf3, bf0, bf1, 5, 6, ic,  0, REC_STD(1, 2))   // d3,d4; make T5,T6
        REGION(1, 2, bf0, bf1, bf2, bf3, 7, 8, ic,  1, REC_STD(3, 0))   // d5,d6; make T7,T8; prefetch x'
        REGION(3, 0, bf2, bf3, bf0, bf1, 1, 2, icn, 0, REC_TANH(1, 2))  // d7,d8; make T1',T2'
    }
#undef REGION
#undef REC_STD
#undef REC_TANH
#undef DRAIN_BAR

    // -------- K-split merge (kh=1 accs added into kh=0 accs), chunked by m --------
#pragma unroll
    for (int m = 0; m < 4; m++) {
        if (kh == 1) {
#pragma unroll
            for (int n = 0; n < 2; n++) {
                char* base = lds + 32768 + (wc * 2 + n) * 4096 + lane * 64;
#pragma unroll
                for (int q = 0; q < 4; q++) {
                    f32x4 v = {acc[m][n][q * 4 + 0], acc[m][n][q * 4 + 1],
                               acc[m][n][q * 4 + 2], acc[m][n][q * 4 + 3]};
                    *(f32x4*)(base + ((q ^ (lane & 3)) << 4)) = v;
                }
            }
        }
        __syncthreads();
        if (kh == 0) {
#pragma unroll
            for (int n = 0; n < 2; n++) {
                const char* base = lds + 32768 + (wc * 2 + n) * 4096 + lane * 64;
#pragma unroll
                for (int q = 0; q < 4; q++) {
                    f32x4 v = *(const f32x4*)(base + ((q ^ (lane & 3)) << 4));
#pragma unroll
                    for (int e = 0; e < 4; e++) acc[m][n][q * 4 + e] += v[e];
                }
            }
        }
        __syncthreads();
    }

    // -------- store (kh=0 waves): C/D col=lane&31, row=(r&3)+8*(r>>2)+4*(lane>>5) --------
    if (kh == 0) {
#pragma unroll
        for (int m = 0; m < 4; m++) {
            int rbase = m0 + m * 32 + ((lane >> 5) << 2);
#pragma unroll
            for (int n = 0; n < 2; n++) {
                int colg = n0 + wc * 64 + n * 32 + (lane & 31);
#pragma unroll
                for (int r = 0; r < 16; r++) {
                    int rowg = rbase + (r & 3) + 8 * (r >> 2);
                    out[(size_t)rowg * 1024 + colg] = acc[m][n][r];
                }
            }
        }
    }
}

extern "C" void kernel_launch(void* const* d_in, const int* in_sizes, int n_in,
                              void* d_out, int out_size, void* d_ws, size_t ws_size,
                              hipStream_t stream) {
    const float* x  = (const float*)d_in[0];
    const float* W  = (const float*)d_in[1];
    const float* sc = (const float*)d_in[2];
    const float* bi = (const float*)d_in[3];
    float* out = (float*)d_out;

    short* Wt2 = (short*)d_ws;
    float* b0  = (float*)((char*)d_ws + WS_B0_OFFSET);
    float* part = out;   // colsum partials staged in d_out (fully overwritten by gemm)

    hipLaunchKernelGGL(wt2_kernel, dim3(9 * 128), dim3(256), 0, stream, W, Wt2);
    hipLaunchKernelGGL(colsum1, dim3(128), dim3(256), 0, stream, W, part);
    hipLaunchKernelGGL(colsum2, dim3(4), dim3(256), 0, stream, part, b0);
    hipLaunchKernelGGL(cheby_gemm, dim3(256), dim3(512), 0, stream, x, Wt2, b0, sc, bi, out);
}